// Round 6
// baseline (157.730 us; speedup 1.0000x reference)
//
#include <hip/hip_runtime.h>
#include <hip/hip_bf16.h>

#define N_SITES 50000
#define N_PERM  12
#define N_NEIGH 8
#define NODE_F  64
#define IN_F    512
#define OUT_F   64
#define N_TILES (N_SITES / 16)   // 3125 exact, one block per tile
#define LN2F    0.69314718055994530942f

#define XCHUNKS (N_SITES * NODE_F / 8)   // 400000 (16B bf16 chunks)
#define WCHUNKS (OUT_F * IN_F / 8)       // 4096
// per-perm staging: 16 slots x (8 rows x 128 B + 16 B pad) = 16640 B
#define SLOT_E  520                       // bf16 elems per slot (1040 B)
#define BUF_E   (16 * SLOT_E)             // 8320 elems = 16640 B

typedef __bf16 bf16x8 __attribute__((ext_vector_type(8)));
typedef float  f32x4  __attribute__((ext_vector_type(4)));

__device__ __forceinline__ unsigned short f32_to_bf16_rne(unsigned int u) {
    u += 0x7FFFu + ((u >> 16) & 1u);
    return (unsigned short)(u >> 16);
}

// Block-uniform dtype probe (R2-R8 proven: live path is fp32 -> 0).
__device__ __forceinline__ int probe_is_bf16(const void* Xorig) {
    int lane = threadIdx.x & 63;
    unsigned short h = ((const unsigned short*)Xorig)[2 * lane];
    int e = (h >> 7) & 0xFF;
    unsigned long long mm = __ballot(e >= 110 && e <= 140);
    return (__popcll(mm) >= 48) ? 1 : 0;
}

__device__ __forceinline__ void pack8(const uint4* src, uint4* dst, int c) {
    uint4 a = src[2 * c], b = src[2 * c + 1];
    uint4 o;
    o.x = (unsigned int)f32_to_bf16_rne(a.x) | ((unsigned int)f32_to_bf16_rne(a.y) << 16);
    o.y = (unsigned int)f32_to_bf16_rne(a.z) | ((unsigned int)f32_to_bf16_rne(a.w) << 16);
    o.z = (unsigned int)f32_to_bf16_rne(b.x) | ((unsigned int)f32_to_bf16_rne(b.y) << 16);
    o.w = (unsigned int)f32_to_bf16_rne(b.z) | ((unsigned int)f32_to_bf16_rne(b.w) << 16);
    dst[c] = o;
}

// One kernel converts X, W (fp32->bf16, or plain copy if already bf16) and
// bias (->f32) into the workspace. Dtype-agnostic main kernel follows.
__global__ void convert_all(const void* __restrict__ Xv, const void* __restrict__ Wv,
                            const void* __restrict__ Bv, uint4* __restrict__ Xb,
                            uint4* __restrict__ Wb, float* __restrict__ Bf) {
    const int isbf = probe_is_bf16(Xv);
    int c = blockIdx.x * blockDim.x + threadIdx.x;
    if (c < XCHUNKS) {
        if (isbf) Xb[c] = ((const uint4*)Xv)[c];
        else      pack8((const uint4*)Xv, Xb, c);
    } else if (c < XCHUNKS + WCHUNKS) {
        int cw = c - XCHUNKS;
        if (isbf) Wb[cw] = ((const uint4*)Wv)[cw];
        else      pack8((const uint4*)Wv, Wb, cw);
    } else if (c < XCHUNKS + WCHUNKS + OUT_F) {
        int i = c - XCHUNKS - WCHUNKS;
        Bf[i] = isbf ? (float)((const __bf16*)Bv)[i] : ((const float*)Bv)[i];
    }
}

__device__ __forceinline__ float softplus_sh(float x) {
    float t = __expf(-fabsf(x));
    return fmaxf(x, 0.f) + 0.69314718056f * __log2f(1.f + t);
}

__device__ __forceinline__ void async16(const __bf16* g, __bf16* l) {
    __builtin_amdgcn_global_load_lds(
        (const __attribute__((address_space(1))) unsigned int*)g,
        (__attribute__((address_space(3))) unsigned int*)l, 16, 0, 0);
}

// R14: producer-consumer wave specialization.
// R13 post-mortem (per-CU accounting): 2.4M ds_read_b128 x 12 cyc + 9.6M
// conflict cyc + DMA LDS-writes = ~168k cyc/CU vs 176k dispatch cycles ->
// the per-CU LDS pipe was ~95% busy = the real wall. (R9/R10 halved reads
// but masked the gain with occupancy collapse / mid-perm barriers.)
// R14 halves LDS reads while keeping 8 waves/CU and the deep DMA pipeline:
//   waves 0-1 = CONSUMERS: fw = wave owns features fw*32..+31 via
//     Wfrag[16][2] (128 VGPR); each ds_read_b128 feeds 2 MFMAs (amp 2x).
//   waves 2-3 = PRODUCERS: only issue global_load_lds (8 slots/perm each,
//     proven octet gather: 8-lane group = one 128 B row, chunk XOR swizzle
//     (c ^ lane>>3) + 16 B/slot pad), pacing with counted vmcnt(16) over a
//     RING-4 buffer -- 3 perms staged ahead, never drained to 0 (T3/T4).
//     All indices u16-packed (50000 < 2^16): 48 VGPR, vmcnt stream pure.
// One s_barrier per perm couples the roles (consumers never wait vmcnt).
// LDS 4 x 16640 = 66.5 KB -> 2 blocks/CU (8 waves). Compute/read formulas
// byte-identical to R8/R13 (proven).
// Decision: ~55 us -> LDS wall confirmed+cleared; ~73 us with conflicts
// halved -> 2.1 TB/s random-gather miss-service is the roofline.

#define BARW(N) do {                                                          \
        asm volatile("s_waitcnt vmcnt(" #N ")" ::: "memory");                 \
        __builtin_amdgcn_s_barrier();                                         \
        asm volatile("" ::: "memory");                                        \
    } while (0)
#define CBAR() do {                                                           \
        asm volatile("" ::: "memory");                                        \
        __builtin_amdgcn_s_barrier();                                         \
        asm volatile("" ::: "memory");                                        \
    } while (0)

__global__ __launch_bounds__(256, 2)
void lcnn_dma(const void* __restrict__ Xorig, const __bf16* __restrict__ Xb,
              const int* __restrict__ NS, const __bf16* __restrict__ Wb,
              const float* __restrict__ Bf, void* __restrict__ outv)
{
    __shared__ __align__(16) __bf16 Abuf[4][BUF_E];   // 4 x 16640 B = 66.5 KB

    const int wave = threadIdx.x >> 6;
    const int lane = threadIdx.x & 63;
    const int tile = blockIdx.x;

    if (wave >= 2) {
        // ---------------- PRODUCER (waves 2,3) ----------------
        const int pw   = wave - 2;            // stages slots pw*8 .. pw*8+7
        const int srow = lane >> 3;
        const int csrc = (lane & 7) ^ srow;   // pre-swizzled source chunk
        const int* ns0p = NS + (size_t)(tile * 16 + srow)     * (N_PERM * N_NEIGH) + pw * 4;
        const int* ns1p = NS + (size_t)(tile * 16 + srow + 8) * (N_PERM * N_NEIGH) + pw * 4;

        // u16-packed indices: pk[p][j] = ns0[k0+j] | ns1[k0+j]<<16, k0=pw*4.
        unsigned int pk[N_PERM][4];
        #pragma unroll
        for (int p = 0; p < N_PERM; ++p) {
            int4 a = *(const int4*)(ns0p + p * N_NEIGH);
            int4 b = *(const int4*)(ns1p + p * N_NEIGH);
            pk[p][0] = ((unsigned)a.x & 0xFFFFu) | ((unsigned)b.x << 16);
            pk[p][1] = ((unsigned)a.y & 0xFFFFu) | ((unsigned)b.y << 16);
            pk[p][2] = ((unsigned)a.z & 0xFFFFu) | ((unsigned)b.z << 16);
            pk[p][3] = ((unsigned)a.w & 0xFFFFu) | ((unsigned)b.w << 16);
        }

#define PSTG(b_, p_) do {                                                     \
            _Pragma("unroll")                                                 \
            for (int i = 0; i < 8; ++i) {                                     \
                unsigned int w_ = pk[p_][i >> 1];                             \
                unsigned int id_ = (i & 1) ? (w_ >> 16) : (w_ & 0xFFFFu);     \
                async16(Xb + (size_t)id_ * NODE_F + csrc * 8,                 \
                        &Abuf[b_][(pw * 8 + i) * SLOT_E]);                    \
            }                                                                 \
        } while (0)

        // Prologue: 3 perms in flight; wait for perm0 only (16 newer stay).
        PSTG(0, 0);
        PSTG(1, 1);
        PSTG(2, 2);
        BARW(16);

        #pragma unroll
        for (int p = 0; p < N_PERM; ++p) {
            if (p + 3 < N_PERM) {
                const int b3 = (p + 3) & 3;
                const int p3 = p + 3;
                PSTG(b3, p3);
            }
            if (p <= 8)       BARW(16);   // drain stage(p+1); p+2,p+3 fly
            else if (p == 9)  BARW(8);    // drain stage(10); stage(11) flies
            else if (p == 10) BARW(0);    // drain stage(11) -- last
            // p == 11: consumers finish alone; producer exits
        }
#undef PSTG
        return;
    }

    // ---------------- CONSUMER (waves 0,1) ----------------
    const int fw   = wave;        // feature half: fw*32 .. fw*32+31
    const int m    = lane & 15;
    const int quad = lane >> 4;
    const int mk   = m & 7;
    const int mh   = m >> 3;

    // W fragments: B[k][n], n = fw*32 + nf*16 + m, k = ks*32 + quad*8 + j
    bf16x8 Wfrag[16][2];
    #pragma unroll
    for (int ks = 0; ks < 16; ++ks) {
        #pragma unroll
        for (int nf = 0; nf < 2; ++nf)
            Wfrag[ks][nf] = *(const bf16x8*)(Wb + (size_t)(fw * 32 + nf * 16 + m) * IN_F
                                             + ks * 32 + quad * 8);
    }
    const float bias0 = Bf[fw * 32 + m];
    const float bias1 = Bf[fw * 32 + 16 + m];

    CBAR();                        // matches producer prologue barrier: perm0 ready

    f32x4 sum0 = {0.f, 0.f, 0.f, 0.f};
    f32x4 sum1 = {0.f, 0.f, 0.f, 0.f};
    #pragma unroll
    for (int p = 0; p < N_PERM; ++p) {
        f32x4 acc0 = {0.f, 0.f, 0.f, 0.f};
        f32x4 acc1 = {0.f, 0.f, 0.f, 0.f};
        const __bf16* bb = &Abuf[p & 3][0];
        #pragma unroll
        for (int ks = 0; ks < 16; ++ks) {
            // row r=(ks>>1)*16+m -> slot t=(ks>>1)*2+mh, in-slot row mk;
            // source chunk j=((ks&1)<<2)|quad lives at LDS chunk j^mk.
            int t_r = (ks >> 1) * 2 + mh;
            int j   = ((ks & 1) << 2) | quad;
            bf16x8 afr = *(const bf16x8*)(bb + t_r * SLOT_E + mk * 64 + ((j ^ mk) << 3));
            acc0 = __builtin_amdgcn_mfma_f32_16x16x32_bf16(afr, Wfrag[ks][0], acc0, 0, 0, 0);
            acc1 = __builtin_amdgcn_mfma_f32_16x16x32_bf16(afr, Wfrag[ks][1], acc1, 0, 0, 0);
        }
        #pragma unroll
        for (int r = 0; r < 4; ++r) {
            sum0[r] += softplus_sh(acc0[r] + bias0);
            sum1[r] += softplus_sh(acc1[r] + bias1);
        }
        if (p < N_PERM - 1) CBAR();   // perm p+1 staged (producer-verified)
    }

    // C: row = quad*4 + r (site), features fw*32 + {0,16} + m (R9/R10-proven)
    const int isbf = probe_is_bf16(Xorig);
    #pragma unroll
    for (int r = 0; r < 4; ++r) {
        size_t pos = (size_t)(tile * 16 + quad * 4 + r) * OUT_F + fw * 32 + m;
        float v0 = sum0[r] - 12.0f * LN2F;
        float v1 = sum1[r] - 12.0f * LN2F;
        if (isbf) {
            ((__bf16*)outv)[pos]      = (__bf16)v0;
            ((__bf16*)outv)[pos + 16] = (__bf16)v1;
        } else {
            ((float*)outv)[pos]      = v0;
            ((float*)outv)[pos + 16] = v1;
        }
    }
}

// Safety net (workspace too small — never seen): direct fp32 compute.
__global__ void lcnn_fallback(const float* __restrict__ X, const int* __restrict__ NS,
                              const float* __restrict__ W, const float* __restrict__ B,
                              float* __restrict__ out) {
    int t = blockIdx.x * blockDim.x + threadIdx.x;
    if (t >= N_SITES * OUT_F) return;
    int sitei = t >> 6, o = t & 63;
    const int* ns = NS + (size_t)sitei * 96;
    float s = 0.f;
    for (int p = 0; p < N_PERM; ++p) {
        float x = B[o];
        for (int n = 0; n < N_NEIGH; ++n) {
            const float* xr = X + (size_t)ns[p * 8 + n] * NODE_F;
            const float* wr = W + (size_t)o * IN_F + n * NODE_F;
            for (int f = 0; f < NODE_F; ++f) x += xr[f] * wr[f];
        }
        s += softplus_sh(x);
    }
    out[t] = s - 12.0f * LN2F;
}

extern "C" void kernel_launch(void* const* d_in, const int* in_sizes, int n_in,
                              void* d_out, int out_size, void* d_ws, size_t ws_size,
                              hipStream_t stream) {
    const void* X  = d_in[0];                // (50000, 64)
    const int*  NS = (const int*)d_in[1];    // (50000, 12, 8) int32
    const void* W  = d_in[2];                // (64, 512)
    const void* B  = d_in[3];                // (64,)

    char* ws = (char*)d_ws;
    __bf16* Xb = (__bf16*)ws;                                     // 6.4 MB
    __bf16* Wb = (__bf16*)(ws + (size_t)XCHUNKS * 16);            // 64 KB
    float*  Bf = (float*)(ws + (size_t)(XCHUNKS + WCHUNKS) * 16); // 256 B
    const bool conv = ws_size >= (size_t)(XCHUNKS + WCHUNKS) * 16 + OUT_F * 4;

    if (conv) {
        int nch = XCHUNKS + WCHUNKS + OUT_F;
        hipLaunchKernelGGL(convert_all, dim3((nch + 255) / 256), dim3(256), 0, stream,
                           X, W, B, (uint4*)Xb, (uint4*)Wb, Bf);
        hipLaunchKernelGGL(lcnn_dma, dim3(N_TILES), dim3(256), 0, stream,
                           X, Xb, NS, Wb, Bf, d_out);
    } else {
        hipLaunchKernelGGL(lcnn_fallback,
                           dim3((N_SITES * OUT_F + 255) / 256), dim3(256), 0, stream,
                           (const float*)X, NS, (const float*)W, (const float*)B,
                           (float*)d_out);
    }
}